// Round 1
// baseline (321.596 us; speedup 1.0000x reference)
//
#include <hip/hip_runtime.h>

// SchroederReverb: 4 series allpass (N=225,556,441,341, g=0.7) then 4 parallel
// feedback combs (N=1116,1188,1277,1356, g=.84,.82,.80,.78) summed.
// Each lagged recurrence y[n] = a*y[n-N] + u[n] decouples into N*W independent
// chains (n = k*N + r, fixed column w). One thread owns one chain; the lagged
// terms are simply the previous iteration's registers. Loads/stores are fully
// coalesced (consecutive lanes = consecutive w).
//
// Reference semantics (verified against the scan): block 0 output forced to 0:
//   allpass: y[n<N]=0; y[n] = x[n] + g*x[n-N] - g*y[n-N]
//   comb:    c[n<N]=0; c[n] = x[n] + g*c[n-N]
//
// Buffers: x -> out(t1) -> ws(t2) -> out(t3) -> ws(t4); combs read ws(t4),
// comb1 overwrites out, combs 2-4 accumulate (RMW). Only one 64 MiB scratch.

constexpr int W    = 128;
constexpr int LOGW = 7;
constexpr int BS   = 128;   // block=128: spreads small-N stage-1 grid over more CUs

// MODE 0: allpass (write), MODE 1: comb (write), MODE 2: comb (accumulate)
// U: software-pipeline depth (independent-address load batch for latency hiding)
template <int MODE, int U>
__global__ __launch_bounds__(BS) void stage_kernel(const float* __restrict__ in,
                                                   float* __restrict__ out,
                                                   int N, float g, int T) {
  int idx = blockIdx.x * BS + threadIdx.x;
  int r = idx >> LOGW;          // chain phase: n = k*N + r
  if (r >= N) return;
  int w = idx & (W - 1);        // column
  int stride = N << LOGW;       // element stride between chain steps
  int pos = (r << LOGW) + w;    // n = r (k = 0)
  int end = T << LOGW;          // 16.7M, fits int

  float xp = in[pos];           // x[n-N] for the next step
  float yp = 0.f;               // y[n-N] (block-0 output is zero)
  if (MODE != 2) out[pos] = 0.f;  // k=0 output is 0; MODE 2 adds 0 => skip
  pos += stride;

  // main loop: batch U independent loads, then the (register-carried) recurrence
  while (pos + (U - 1) * stride < end) {
    float xs[U], os[U];
#pragma unroll
    for (int u = 0; u < U; ++u) xs[u] = in[pos + u * stride];
    if (MODE == 2) {
#pragma unroll
      for (int u = 0; u < U; ++u) os[u] = out[pos + u * stride];
    }
#pragma unroll
    for (int u = 0; u < U; ++u) {
      float x = xs[u];
      float y = (MODE == 0) ? (x + g * xp - g * yp) : (x + g * yp);
      out[pos + u * stride] = (MODE == 2) ? (os[u] + y) : y;
      xp = x;
      yp = y;
    }
    pos += U * stride;
  }
  // tail
  while (pos < end) {
    float x = in[pos];
    float y = (MODE == 0) ? (x + g * xp - g * yp) : (x + g * yp);
    if (MODE == 2) out[pos] += y; else out[pos] = y;
    xp = x;
    yp = y;
    pos += stride;
  }
}

static inline int grid_for(int N) { return (N * W + BS - 1) / BS; }

extern "C" void kernel_launch(void* const* d_in, const int* in_sizes, int n_in,
                              void* d_out, int out_size, void* d_ws, size_t ws_size,
                              hipStream_t stream) {
  const float* x = (const float*)d_in[0];
  float* out = (float*)d_out;
  float* ws0 = (float*)d_ws;          // needs T*W*4 = 64 MiB of scratch
  const int T = in_sizes[0] / W;      // 131072

  constexpr int U = 16;
  const float gA = 0.7f;

  // series allpass chain, ping-pong out <-> ws
  hipLaunchKernelGGL((stage_kernel<0, U>), dim3(grid_for(225)), dim3(BS), 0, stream,
                     x,   out, 225, gA, T);
  hipLaunchKernelGGL((stage_kernel<0, U>), dim3(grid_for(556)), dim3(BS), 0, stream,
                     out, ws0, 556, gA, T);
  hipLaunchKernelGGL((stage_kernel<0, U>), dim3(grid_for(441)), dim3(BS), 0, stream,
                     ws0, out, 441, gA, T);
  hipLaunchKernelGGL((stage_kernel<0, U>), dim3(grid_for(341)), dim3(BS), 0, stream,
                     out, ws0, 341, gA, T);

  // parallel comb bank: comb1 overwrites out, combs 2-4 accumulate
  hipLaunchKernelGGL((stage_kernel<1, U>), dim3(grid_for(1116)), dim3(BS), 0, stream,
                     ws0, out, 1116, 0.84f, T);
  hipLaunchKernelGGL((stage_kernel<2, U>), dim3(grid_for(1188)), dim3(BS), 0, stream,
                     ws0, out, 1188, 0.82f, T);
  hipLaunchKernelGGL((stage_kernel<2, U>), dim3(grid_for(1277)), dim3(BS), 0, stream,
                     ws0, out, 1277, 0.80f, T);
  hipLaunchKernelGGL((stage_kernel<2, U>), dim3(grid_for(1356)), dim3(BS), 0, stream,
                     ws0, out, 1356, 0.78f, T);
}

// Round 2
// 305.945 us; speedup vs baseline: 1.0512x; 1.0512x over previous
//
#include <hip/hip_runtime.h>
#include <math.h>

// SchroederReverb: 4 series allpass (N=225,556,441,341, g=0.7) then 4 parallel
// feedback combs (N=1116,1188,1277,1356, g=.84,.82,.80,.78) summed.
//
// Each lagged recurrence y[n] = a*y[n-N] + u[n] decouples into N*W chains
// (n = k*N + r, column w). Round-1 gave one thread per chain -> 4% occupancy
// (N=225 => 450 waves chip-wide), latency-bound at 1.7 TB/s.
//
// Round 2: split each chain into S segments held in ONE block.
//   thread (s, w): marches its segment with assumed y_in = 0, keeping the L
//   local outputs in registers (loop fully unrolled). Since the recurrence is
//   affine in the incoming state: y_true[k0+t] = y_loc[t] + a^(t+1) * Y_in.
//   Carries C_s = y_loc[L-1] go through LDS (one __syncthreads); each thread
//   folds its prefix Y_in = sum_j a^(L*(s-1-j)) C_j, then applies the
//   correction during the single store pass. Traffic unchanged (1R+1W per
//   element), parallelism multiplied by S.
//
// Semantics (identical to passing round-1 kernel):
//   allpass: y[k=0]=0; y[k] = (x[k] + g*x[k-1]) - g*y[k-1]   (per chain)
//   comb:    y[k=0]=0; y[k] =  x[k]             + g*y[k-1]
//
// Buffers: x -> out(t1) -> ws(t2) -> out(t3) -> ws(t4); comb1 writes out,
// combs 2-4 accumulate (RMW). One 64 MiB scratch.

constexpr int W    = 128;
constexpr int LOGW = 7;

// ---------------- segmented in-block chain-scan kernel ----------------
// MODE 0: allpass (write), MODE 1: comb (write), MODE 2: comb (accumulate)
// S segments/chain, L steps/segment. Block = S*64 threads: wave = one segment
// x 64 consecutive columns (coalesced 256B). Grid = 2*N blocks (2 w-halves).
template <int MODE, int S, int L>
__global__ __launch_bounds__(S * 64)
void stage_seg(const float* __restrict__ in, float* __restrict__ out,
               int N, float g, float aL, int T) {
  const float a = (MODE == 0) ? -g : g;
  __shared__ float C[S][64];

  const int tid = threadIdx.x;
  const int s   = tid >> 6;          // segment index (wave-uniform)
  const int wl  = tid & 63;
  const int bx  = blockIdx.x;
  const int r   = bx >> 1;           // chain phase: n = k*N + r
  const int w   = ((bx & 1) << 6) | wl;
  const int stride = N << LOGW;
  const int end    = T << LOGW;
  const int k0   = s * L;
  const int pos0 = ((k0 * N + r) << LOGW) + w;

  // ---- march segment with assumed y_in = 0; locals stay in registers ----
  float y[L];
  float xp = 0.f;
  if (MODE == 0) {
    if (s == 0) {
      xp = in[pos0];                       // x[k=0] (always in range)
    } else {
      const int pp = pos0 - stride;        // k0-1 >= 0 always
      xp = (pp < end) ? in[pp] : 0.f;
    }
  }
  float yprev = 0.f;
  int pos = pos0;
#pragma unroll
  for (int j = 0; j < L; ++j) {
    float yj;
    if (j == 0 && s == 0) {
      yj = 0.f;                            // forced-zero block 0; xp = x[0]
    } else {
      float x = (pos < end) ? in[pos] : 0.f;
      float u = (MODE == 0) ? fmaf(g, xp, x) : x;
      yj = fmaf(a, yprev, u);
      xp = x;
    }
    y[j] = yj;
    yprev = yj;
    pos += stride;
  }

  // ---- exchange carries, fold incoming state ----
  C[s][wl] = yprev;                        // local end value (y_in = 0)
  __syncthreads();
  float Yin = 0.f;                         // true y at k0-1
  for (int j = 0; j < s; ++j) Yin = fmaf(aL, Yin, C[j][wl]);

  // ---- correction + store ----
  float p = a;
  pos = pos0;
#pragma unroll
  for (int j = 0; j < L; ++j) {
    if (pos < end) {
      float val = fmaf(p, Yin, y[j]);
      if (MODE == 2) val += out[pos];
      out[pos] = val;
    }
    p *= a;
    pos += stride;
  }
}

// ---------------- round-1 fallback (any T) ----------------
template <int MODE, int U>
__global__ __launch_bounds__(128)
void stage_simple(const float* __restrict__ in, float* __restrict__ out,
                  int N, float g, int T) {
  int idx = blockIdx.x * 128 + threadIdx.x;
  int r = idx >> LOGW;
  if (r >= N) return;
  int w = idx & (W - 1);
  int stride = N << LOGW;
  int pos = (r << LOGW) + w;
  int end = T << LOGW;
  float xp = in[pos];
  float yp = 0.f;
  if (MODE != 2) out[pos] = 0.f;
  pos += stride;
  while (pos + (U - 1) * stride < end) {
    float xs[U], os[U];
#pragma unroll
    for (int u = 0; u < U; ++u) xs[u] = in[pos + u * stride];
    if (MODE == 2) {
#pragma unroll
      for (int u = 0; u < U; ++u) os[u] = out[pos + u * stride];
    }
#pragma unroll
    for (int u = 0; u < U; ++u) {
      float x = xs[u];
      float y = (MODE == 0) ? (x + g * xp - g * yp) : (x + g * yp);
      out[pos + u * stride] = (MODE == 2) ? (os[u] + y) : y;
      xp = x; yp = y;
    }
    pos += U * stride;
  }
  while (pos < end) {
    float x = in[pos];
    float y = (MODE == 0) ? (x + g * xp - g * yp) : (x + g * yp);
    if (MODE == 2) out[pos] += y; else out[pos] = y;
    xp = x; yp = y;
    pos += stride;
  }
}

extern "C" void kernel_launch(void* const* d_in, const int* in_sizes, int n_in,
                              void* d_out, int out_size, void* d_ws, size_t ws_size,
                              hipStream_t stream) {
  const float* x = (const float*)d_in[0];
  float* out = (float*)d_out;
  float* ws  = (float*)d_ws;              // needs T*W*4 = 64 MiB scratch
  const int T = in_sizes[0] / W;          // 131072

  if (T == 131072) {
    // K = ceil(131072/N): 225->583, 556->236, 441->298, 341->385,
    //                     1116->118, 1188->111, 1277->103, 1356->97
    // L = ceil(K/S); checked (S-1)*L <= Kmin-1 so only the last segment is
    // ragged (its carry is never consumed).
#define LAUNCH_SEG(MODE, S, L, IN, OUT, N, G)                                  \
    do {                                                                       \
      float a_  = (MODE == 0) ? -(G) : (G);                                    \
      float aL_ = (float)pow((double)a_, (double)(L));                         \
      hipLaunchKernelGGL((stage_seg<MODE, S, L>), dim3((N) * 2),               \
                         dim3((S) * 64), 0, stream, IN, OUT, N, G, aL_, T);    \
    } while (0)

    // series allpass chain, ping-pong out <-> ws
    LAUNCH_SEG(0, 16, 37, x,   out, 225,  0.7f);
    LAUNCH_SEG(0,  8, 30, out, ws,  556,  0.7f);
    LAUNCH_SEG(0,  8, 38, ws,  out, 441,  0.7f);
    LAUNCH_SEG(0,  8, 49, out, ws,  341,  0.7f);
    // parallel comb bank: comb1 overwrites out, combs 2-4 accumulate
    LAUNCH_SEG(1,  4, 30, ws,  out, 1116, 0.84f);
    LAUNCH_SEG(2,  4, 28, ws,  out, 1188, 0.82f);
    LAUNCH_SEG(2,  4, 26, ws,  out, 1277, 0.80f);
    LAUNCH_SEG(2,  4, 25, ws,  out, 1356, 0.78f);
#undef LAUNCH_SEG
  } else {
    constexpr int U = 16;
    auto grid_for = [](int N) { return (N * W + 127) / 128; };
    hipLaunchKernelGGL((stage_simple<0, U>), dim3(grid_for(225)),  dim3(128), 0, stream, x,   out, 225,  0.7f,  T);
    hipLaunchKernelGGL((stage_simple<0, U>), dim3(grid_for(556)),  dim3(128), 0, stream, out, ws,  556,  0.7f,  T);
    hipLaunchKernelGGL((stage_simple<0, U>), dim3(grid_for(441)),  dim3(128), 0, stream, ws,  out, 441,  0.7f,  T);
    hipLaunchKernelGGL((stage_simple<0, U>), dim3(grid_for(341)),  dim3(128), 0, stream, out, ws,  341,  0.7f,  T);
    hipLaunchKernelGGL((stage_simple<1, U>), dim3(grid_for(1116)), dim3(128), 0, stream, ws,  out, 1116, 0.84f, T);
    hipLaunchKernelGGL((stage_simple<2, U>), dim3(grid_for(1188)), dim3(128), 0, stream, ws,  out, 1188, 0.82f, T);
    hipLaunchKernelGGL((stage_simple<2, U>), dim3(grid_for(1277)), dim3(128), 0, stream, ws,  out, 1277, 0.80f, T);
    hipLaunchKernelGGL((stage_simple<2, U>), dim3(grid_for(1356)), dim3(128), 0, stream, ws,  out, 1356, 0.78f, T);
  }
}